// Round 2
// baseline (222.836 us; speedup 1.0000x reference)
//
#include <hip/hip_runtime.h>
#include <hip/hip_bf16.h>

typedef unsigned short u16;
typedef unsigned int u32;
typedef __attribute__((ext_vector_type(2))) float f32x2;
typedef __attribute__((ext_vector_type(4))) float f32x4;
typedef __attribute__((ext_vector_type(4))) u16 u16x4;
typedef __attribute__((ext_vector_type(8))) u16 u16x8;
typedef __attribute__((ext_vector_type(8))) __bf16 bf16x8;

#define B_ 32
#define T_ 2048
#define MID_ 1024
#define TOPIC_ 512
#define H_ 256
#define ROWS_ 32            // t-rows per fused workgroup
#define NCH_ (T_ / ROWS_)   // 64 chunks per batch

// fp32 -> bf16 RNE
static __device__ __forceinline__ u16 f2bf(float x) {
    u32 u = __float_as_uint(x);
    u = (u + 0x7FFFu + ((u >> 16) & 1u)) >> 16;
    return (u16)u;
}
static __device__ __forceinline__ float bf2f(u32 lo16) {
    return __uint_as_float(lo16 << 16);
}

// ---------------- prep kernels ----------------

// enc_out[b][h] = Ua_b[h] + sum_d enc[b][d] * Ua_w[h][d]
__global__ __launch_bounds__(256) void k_enc(const float* __restrict__ enc,
                                             const float* __restrict__ Ua_w,
                                             const float* __restrict__ Ua_b,
                                             float* __restrict__ enc_out) {
    __shared__ float es[TOPIC_];
    const int b = blockIdx.x, tid = threadIdx.x;
    es[tid]       = enc[b * TOPIC_ + tid];
    es[tid + 256] = enc[b * TOPIC_ + 256 + tid];
    __syncthreads();
    const float* ua = Ua_w + (size_t)tid * TOPIC_;
    float s = Ua_b[tid];
    #pragma unroll 4
    for (int d = 0; d < TOPIC_; d += 4) {
        f32x4 u = *(const f32x4*)(ua + d);
        s += u[0] * es[d] + u[1] * es[d + 1] + u[2] * es[d + 2] + u[3] * es[d + 3];
    }
    enc_out[b * H_ + tid] = s;
}

// vsum = sum_h v_w[h]
__global__ void k_vsum(const float* __restrict__ v_w, float* __restrict__ vsum) {
    const int lane = threadIdx.x;  // 64 threads
    float s = v_w[lane] + v_w[lane + 64] + v_w[lane + 128] + v_w[lane + 192];
    #pragma unroll
    for (int m = 32; m; m >>= 1) s += __shfl_xor(s, m, 64);
    if (lane == 0) *vsum = s;
}

// Wa (fp32 [256][1024]) -> bf16, K-step-major layout [ks=32][h=256][kk=32]
__global__ __launch_bounds__(256) void k_wacvt(const float* __restrict__ Wa,
                                               u16* __restrict__ wa16s) {
    const int e0 = blockIdx.x * 1024 + threadIdx.x;
    #pragma unroll
    for (int i = 0; i < 4; ++i) {
        const int e = e0 + 256 * i;        // e = h*1024 + k
        const int h = e >> 10, k = e & 1023;
        wa16s[(k >> 5) * (H_ * 32) + h * 32 + (k & 31)] = f2bf(Wa[e]);
    }
}

// ---------------- fused: per 32-row chunk, logits -> local softmax -> partial wsum ----------------
// grid 2048 = (b:32, chunk:64), 512 threads = 8 waves.
// LDS: dec chunk as bf16 [32][1024], XOR-swizzled (elem ^= (row&7)<<3).
// GEMM: wave w -> row-tile rt=w&1 (16 rows), col-half ch=w>>1 (64 cols = 4 MFMA tiles).
// B (Wa) streamed straight from L1/L2 (16KB/ks slice, 4x wave redundancy served by L1).
__global__ __launch_bounds__(512, 4) void k_fused(const float* __restrict__ dec,
                                                  const int* __restrict__ masks,
                                                  const float* __restrict__ enc_out,
                                                  const float* __restrict__ v_w,
                                                  const float* __restrict__ vsum_p,
                                                  const u16* __restrict__ wa16s,
                                                  float* __restrict__ po,
                                                  float* __restrict__ pms) {
    __shared__ u16 hi[ROWS_ * MID_];     // 64 KB
    __shared__ float encs[H_];
    __shared__ float vs[H_];
    __shared__ float partc[4][ROWS_];
    __shared__ float ev[ROWS_];

    const int tid = threadIdx.x;
    const int wg = blockIdx.x;
    const int b = wg >> 6, chunk = wg & (NCH_ - 1);
    const int lane = tid & 63, wave = tid >> 6;
    const int rt = wave & 1, ch = wave >> 1;
    const int rl = lane & 15, kgrp = lane >> 4;

    // ---- phase 1: stage dec chunk -> LDS bf16 (swizzled); preload enc/v ----
    if (tid < H_) { encs[tid] = enc_out[b * H_ + tid]; vs[tid] = v_w[tid]; }
    const float* src = dec + (size_t)(b * T_ + chunk * ROWS_) * MID_;
    #pragma unroll
    for (int i = 0; i < 16; ++i) {
        const int e = i * 2048 + tid * 4;          // element in [0, 32768)
        f32x4 d = *(const f32x4*)(src + e);
        const int row = e >> 10, col = e & 1023;
        u16x4 h4;
        h4[0] = f2bf(d[0]); h4[1] = f2bf(d[1]); h4[2] = f2bf(d[2]); h4[3] = f2bf(d[3]);
        *(u16x4*)&hi[row * MID_ + (col ^ ((row & 7) << 3))] = h4;   // 8B write, 2-way free
    }
    __syncthreads();

    // ---- phase 2: GEMM 32x256, K=1024; A from LDS, B from global (L1/L2) ----
    f32x4 acc[4];
    const f32x4 z = {0.f, 0.f, 0.f, 0.f};
    acc[0] = z; acc[1] = z; acc[2] = z; acc[3] = z;

    const int arow = rt * 16 + rl;
    const int asw = (arow & 7) << 3;
    const u16* wb = wa16s + (ch * 64 + rl) * 32 + kgrp * 8;

    #pragma unroll 2
    for (int ks = 0; ks < 32; ++ks) {
        bf16x8 af = *(const bf16x8*)&hi[arow * MID_ + ((ks * 32 + kgrp * 8) ^ asw)];
        const u16* wp = wb + ks * (H_ * 32);
        #pragma unroll
        for (int t4 = 0; t4 < 4; ++t4) {
            bf16x8 bf = *(const bf16x8*)(wp + t4 * 512);   // tile stride 16 h * 32 k
            acc[t4] = __builtin_amdgcn_mfma_f32_16x16x32_bf16(af, bf, acc[t4], 0, 0, 0);
        }
    }

    // ---- phase 3: logits + chunk-local softmax ----
    float p0 = 0.f, p1 = 0.f, p2 = 0.f, p3 = 0.f;
    #pragma unroll
    for (int t4 = 0; t4 < 4; ++t4) {
        const int col = ch * 64 + t4 * 16 + rl;
        const float e0 = encs[col], vv = vs[col];
        p0 += vv * tanhf(e0 + acc[t4][0]);
        p1 += vv * tanhf(e0 + acc[t4][1]);
        p2 += vv * tanhf(e0 + acc[t4][2]);
        p3 += vv * tanhf(e0 + acc[t4][3]);
    }
    #pragma unroll
    for (int m = 1; m < 16; m <<= 1) {
        p0 += __shfl_xor(p0, m, 64);
        p1 += __shfl_xor(p1, m, 64);
        p2 += __shfl_xor(p2, m, 64);
        p3 += __shfl_xor(p3, m, 64);
    }
    if (rl == 0) {
        const int r = rt * 16 + kgrp * 4;    // C layout: row = (lane>>4)*4 + j
        partc[ch][r + 0] = p0;
        partc[ch][r + 1] = p1;
        partc[ch][r + 2] = p2;
        partc[ch][r + 3] = p3;
    }
    __syncthreads();

    if (wave == 0) {
        const int r = lane & 31;             // lanes 32..63 duplicate (harmless)
        float a = partc[0][r] + partc[1][r] + partc[2][r] + partc[3][r];
        const int mk = masks[b * T_ + chunk * ROWS_ + r];
        a = mk ? a : -(*vsum_p);             // tanh(-inf) = -1 -> logit = -sum(v)
        float mx = a;
        #pragma unroll
        for (int m = 1; m < 32; m <<= 1) mx = fmaxf(mx, __shfl_xor(mx, m, 64));
        const float e = expf(a - mx);
        float s = e;
        #pragma unroll
        for (int m = 1; m < 32; m <<= 1) s += __shfl_xor(s, m, 64);
        if (lane < 32) ev[r] = e;
        if (lane == 0) { pms[wg * 2] = mx; pms[wg * 2 + 1] = s; }
    }
    __syncthreads();

    // ---- phase 4: partial weighted sum from bf16 LDS copy ----
    f32x2 o = {0.f, 0.f};
    const int m2 = tid * 2;                  // columns m2, m2+1
    #pragma unroll 8
    for (int t = 0; t < ROWS_; ++t) {
        const u32 h2 = *(const u32*)&hi[t * MID_ + (m2 ^ ((t & 7) << 3))];
        const float w = ev[t];
        o[0] += w * bf2f(h2 & 0xFFFFu);
        o[1] += w * bf2f(h2 >> 16);
    }
    *(f32x2*)&po[(size_t)wg * MID_ + m2] = o;
}

// ---------------- combine: out[b][m] = sum_c w_c * o_c[m] ----------------
__global__ __launch_bounds__(256) void k_comb(const float* __restrict__ po,
                                              const float* __restrict__ pms,
                                              float* __restrict__ out) {
    __shared__ float wch[NCH_];
    const int b = blockIdx.x, tid = threadIdx.x;
    if (tid < 64) {
        const float mi = pms[(b * NCH_ + tid) * 2];
        const float si = pms[(b * NCH_ + tid) * 2 + 1];
        float M = mi;
        #pragma unroll
        for (int m = 1; m < 64; m <<= 1) M = fmaxf(M, __shfl_xor(M, m, 64));
        const float w = expf(mi - M);
        float D = si * w;
        #pragma unroll
        for (int m = 1; m < 64; m <<= 1) D += __shfl_xor(D, m, 64);
        wch[tid] = w / D;
    }
    __syncthreads();
    #pragma unroll
    for (int i = 0; i < 4; ++i) {
        const int mcol = i * 256 + tid;
        float s = 0.f;
        for (int c = 0; c < NCH_; ++c)
            s += wch[c] * po[((size_t)b * NCH_ + c) * MID_ + mcol];
        out[b * MID_ + mcol] = s;
    }
}

extern "C" void kernel_launch(void* const* d_in, const int* in_sizes, int n_in,
                              void* d_out, int out_size, void* d_ws, size_t ws_size,
                              hipStream_t stream) {
    const float* enc   = (const float*)d_in[0];
    const float* dec   = (const float*)d_in[1];
    const int*   masks = (const int*)d_in[2];
    const float* Ua_w  = (const float*)d_in[3];
    const float* Ua_b  = (const float*)d_in[4];
    const float* Wa_w  = (const float*)d_in[5];
    const float* v_w   = (const float*)d_in[6];
    float* out = (float*)d_out;

    char* ws = (char*)d_ws;
    float* enc_out = (float*)(ws + 0);         // 32 KB
    float* vsum    = (float*)(ws + 32768);     // 4 B (padded to 32 KB)
    u16*   wa16s   = (u16*)(ws + 65536);       // 512 KB
    float* pms     = (float*)(ws + 589824);    // 16 KB  (2048 x {max, sum})
    float* po      = (float*)(ws + 606208);    // 8 MB   (2048 x 1024 partial sums)
    // total ws use: ~9.0 MB

    k_enc<<<dim3(B_), dim3(256), 0, stream>>>(enc, Ua_w, Ua_b, enc_out);
    k_vsum<<<dim3(1), dim3(64), 0, stream>>>(v_w, vsum);
    k_wacvt<<<dim3(256), dim3(256), 0, stream>>>(Wa_w, wa16s);
    k_fused<<<dim3(B_ * NCH_), dim3(512), 0, stream>>>(dec, masks, enc_out, v_w, vsum,
                                                       wa16s, po, pms);
    k_comb<<<dim3(B_), dim3(256), 0, stream>>>(po, pms, out);
}

// Round 3
// 152.890 us; speedup vs baseline: 1.4575x; 1.4575x over previous
//
#include <hip/hip_runtime.h>
#include <hip/hip_bf16.h>

typedef unsigned short u16;
typedef unsigned int u32;
typedef __attribute__((ext_vector_type(4))) float f32x4;
typedef __attribute__((ext_vector_type(4))) u16 u16x4;
typedef __attribute__((ext_vector_type(8))) u16 u16x8;
typedef __attribute__((ext_vector_type(8))) __bf16 bf16x8;

#define B_ 32
#define T_ 2048
#define MID_ 1024
#define TOPIC_ 512
#define H_ 256
#define MBLK_ 128

// fp32 -> bf16 RNE
static __device__ __forceinline__ u16 f2bf(float x) {
    u32 u = __float_as_uint(x);
    u = (u + 0x7FFFu + ((u >> 16) & 1u)) >> 16;
    return (u16)u;
}

static __device__ __forceinline__ void gl_lds16(const u16* g, u16* l) {
    __builtin_amdgcn_global_load_lds((const __attribute__((address_space(1))) void*)(const void*)g,
                                     (__attribute__((address_space(3))) void*)(void*)l,
                                     16, 0, 0);
}

// ---------------- prep kernels ----------------

// enc_out[b][h] = Ua_b[h] + sum_d enc[b][d] * Ua_w[h][d]
__global__ __launch_bounds__(256) void k_enc(const float* __restrict__ enc,
                                             const float* __restrict__ Ua_w,
                                             const float* __restrict__ Ua_b,
                                             float* __restrict__ enc_out) {
    __shared__ float es[TOPIC_];
    const int b = blockIdx.x, tid = threadIdx.x;
    es[tid]       = enc[b * TOPIC_ + tid];
    es[tid + 256] = enc[b * TOPIC_ + 256 + tid];
    __syncthreads();
    const float* ua = Ua_w + (size_t)tid * TOPIC_;
    float s = Ua_b[tid];
    #pragma unroll 4
    for (int d = 0; d < TOPIC_; d += 4) {
        f32x4 u = *(const f32x4*)(ua + d);
        s += u[0] * es[d] + u[1] * es[d + 1] + u[2] * es[d + 2] + u[3] * es[d + 3];
    }
    enc_out[b * H_ + tid] = s;
}

// vsum = sum_h v_w[h]
__global__ void k_vsum(const float* __restrict__ v_w, float* __restrict__ vsum) {
    const int lane = threadIdx.x;  // 64 threads
    float s = v_w[lane] + v_w[lane + 64] + v_w[lane + 128] + v_w[lane + 192];
    #pragma unroll
    for (int m = 32; m; m >>= 1) s += __shfl_xor(s, m, 64);
    if (lane == 0) *vsum = s;
}

// Wa (fp32 [256][1024]) -> bf16, layout [ks=32 slices][8192 u16], each slice a
// [h=256][kk=32] tile PRE-SWIZZLED: idx = (h*32+kk) ^ ((h&7)<<3).  GEMM stages it
// linearly via global_load_lds and reads with the same XOR -> conflict-free.
__global__ __launch_bounds__(256) void k_wacvt(const float* __restrict__ Wa,
                                               u16* __restrict__ wa16s) {
    const int h = blockIdx.x, tid = threadIdx.x;   // 256 blocks x 256 threads
    const int k = tid * 4;
    f32x4 w = *(const f32x4*)(Wa + h * MID_ + k);
    u16x4 h4;
    h4[0] = f2bf(w[0]); h4[1] = f2bf(w[1]); h4[2] = f2bf(w[2]); h4[3] = f2bf(w[3]);
    const int idx = (k >> 5) * 8192 + ((h * 32 + (k & 31)) ^ ((h & 7) << 3));
    *(u16x4*)&wa16s[idx] = h4;
}

// ---------------- pass 1: logits GEMM (M=65536 x N=256 x K=1024, bf16 MFMA) ----------------
// 512 WGs x 128 rows. 8 waves as 2(row) x 4(col); wave tile 64x64 -> acc[4][4] f32x4.
// A (dec fp32) -> regs (prefetch 2 K-steps ahead) -> bf16 -> LDS (XOR-swizzled).
// B (wa16s) -> LDS via global_load_lds (pre-swizzled source, linear dest).
__global__ __launch_bounds__(512, 2) void k_logits2(const float* __restrict__ dec,
                                                    const int* __restrict__ masks,
                                                    const float* __restrict__ enc_out,
                                                    const float* __restrict__ v_w,
                                                    const float* __restrict__ vsum_p,
                                                    const u16* __restrict__ wa16s,
                                                    float* __restrict__ a_out) {
    __shared__ __attribute__((aligned(16))) u16 Ab[2][MBLK_ * 32];  // 2 x 8 KB
    __shared__ __attribute__((aligned(16))) u16 Bb[2][H_ * 32];     // 2 x 16 KB
    __shared__ float partc[4][MBLK_];

    const int tid = threadIdx.x;
    const int lane = tid & 63, wave = tid >> 6;
    const int wrow = wave & 1, wcol = wave >> 1;
    const int rl = lane & 15, kgrp = lane >> 4;
    const int r0 = blockIdx.x * MBLK_;
    const int b = r0 >> 11;

    // enc/v per-lane registers (4 col-subtiles each)
    float encr[4], vr[4];
    #pragma unroll
    for (int tc = 0; tc < 4; ++tc) {
        const int h = wcol * 64 + tc * 16 + rl;
        encr[tc] = enc_out[b * H_ + h];
        vr[tc] = v_w[h];
    }

    // A staging: thread -> (row, 8-elem k-chunk)
    const int arow = tid >> 2, koff = (tid & 3) * 8;
    const float* asrc = dec + (size_t)(r0 + arow) * MID_ + koff;
    const int awr = (arow * 32 + koff) ^ ((arow & 7) << 3);

    // B staging: per-lane global src, wave-uniform LDS dest
    const u16* bsrc = wa16s + wave * 1024 + lane * 8;
    const int bdst = wave * 1024;

    // fragment read offsets (u16 units, swizzled)
    int ard[4], brd[4];
    #pragma unroll
    for (int t = 0; t < 4; ++t) {
        const int r = wrow * 64 + t * 16 + rl;
        ard[t] = (r * 32 + kgrp * 8) ^ ((rl & 7) << 3);
        const int h = wcol * 64 + t * 16 + rl;
        brd[t] = (h * 32 + kgrp * 8) ^ ((rl & 7) << 3);
    }

    f32x4 acc[4][4];
    const f32x4 z = {0.f, 0.f, 0.f, 0.f};
    #pragma unroll
    for (int i = 0; i < 4; ++i)
        #pragma unroll
        for (int j = 0; j < 4; ++j) acc[i][j] = z;

    // ---- prologue: A(0),A(1) -> regs; B(0) -> Bb[0]; A(0) -> Ab[0] ----
    f32x4 s0a = *(const f32x4*)(asrc);
    f32x4 s0b = *(const f32x4*)(asrc + 4);
    f32x4 s1a = *(const f32x4*)(asrc + 32);
    f32x4 s1b = *(const f32x4*)(asrc + 36);
    asrc += 64;
    gl_lds16(bsrc, &Bb[0][bdst]);
    gl_lds16(bsrc + 512, &Bb[0][bdst + 512]);
    {
        u16x8 h8;
        #pragma unroll
        for (int i = 0; i < 4; ++i) { h8[i] = f2bf(s0a[i]); h8[4 + i] = f2bf(s0b[i]); }
        *(u16x8*)&Ab[0][awr] = h8;
    }
    __syncthreads();

    #define COMPUTE(BUF)                                                          \
        do {                                                                      \
            bf16x8 af[4], bfv[4];                                                 \
            _Pragma("unroll") for (int t = 0; t < 4; ++t)                         \
                af[t] = *(const bf16x8*)&Ab[BUF][ard[t]];                         \
            _Pragma("unroll") for (int t = 0; t < 4; ++t)                         \
                bfv[t] = *(const bf16x8*)&Bb[BUF][brd[t]];                        \
            _Pragma("unroll") for (int tr = 0; tr < 4; ++tr)                      \
                _Pragma("unroll") for (int tc = 0; tc < 4; ++tc)                  \
                    acc[tr][tc] = __builtin_amdgcn_mfma_f32_16x16x32_bf16(        \
                        af[tr], bfv[tc], acc[tr][tc], 0, 0, 0);                   \
        } while (0)

    #pragma unroll 1
    for (int ks = 0; ks < 32; ks += 2) {
        // ---- even step: compute buf0 (slice ks); stage slice ks+1 -> buf1 ----
        {
            gl_lds16(bsrc + (ks + 1) * 8192, &Bb[1][bdst]);
            gl_lds16(bsrc + (ks + 1) * 8192 + 512, &Bb[1][bdst + 512]);
            if (ks + 2 < 32) {  // issue A(ks+2) loads before the dependent write below
                s0a = *(const f32x4*)(asrc);
                s0b = *(const f32x4*)(asrc + 4);
                asrc += 32;
            }
            u16x8 h8;  // A(ks+1) from s1 (loaded 2 steps ago)
            #pragma unroll
            for (int i = 0; i < 4; ++i) { h8[i] = f2bf(s1a[i]); h8[4 + i] = f2bf(s1b[i]); }
            *(u16x8*)&Ab[1][awr] = h8;
        }
        COMPUTE(0);
        __syncthreads();

        // ---- odd step: compute buf1 (slice ks+1); stage slice ks+2 -> buf0 ----
        if (ks + 2 < 32) {
            gl_lds16(bsrc + (ks + 2) * 8192, &Bb[0][bdst]);
            gl_lds16(bsrc + (ks + 2) * 8192 + 512, &Bb[0][bdst + 512]);
            if (ks + 3 < 32) {
                s1a = *(const f32x4*)(asrc);
                s1b = *(const f32x4*)(asrc + 4);
                asrc += 32;
            }
            u16x8 h8;  // A(ks+2) from s0
            #pragma unroll
            for (int i = 0; i < 4; ++i) { h8[i] = f2bf(s0a[i]); h8[4 + i] = f2bf(s0b[i]); }
            *(u16x8*)&Ab[0][awr] = h8;
        }
        COMPUTE(1);
        __syncthreads();
    }
    #undef COMPUTE

    // ---- epilogue: logits ----
    // acc[tr][tc][j] = C[t-row = wrow*64+tr*16+kgrp*4+j][h = wcol*64+tc*16+rl]
    float part[4][4];
    #pragma unroll
    for (int tr = 0; tr < 4; ++tr)
        #pragma unroll
        for (int j = 0; j < 4; ++j) {
            float p = 0.f;
            #pragma unroll
            for (int tc = 0; tc < 4; ++tc)
                p += vr[tc] * tanhf(encr[tc] + acc[tr][tc][j]);
            part[tr][j] = p;
        }
    #pragma unroll
    for (int m = 1; m < 16; m <<= 1)
        #pragma unroll
        for (int tr = 0; tr < 4; ++tr)
            #pragma unroll
            for (int j = 0; j < 4; ++j)
                part[tr][j] += __shfl_xor(part[tr][j], m, 64);
    if (rl == 0) {
        #pragma unroll
        for (int tr = 0; tr < 4; ++tr)
            #pragma unroll
            for (int j = 0; j < 4; ++j)
                partc[wcol][wrow * 64 + tr * 16 + kgrp * 4 + j] = part[tr][j];
    }
    __syncthreads();

    if (wcol == 0) {  // waves 0,1 -> 128 rows
        const int tl = wrow * 64 + lane;
        float a = partc[0][tl] + partc[1][tl] + partc[2][tl] + partc[3][tl];
        const int t = (r0 + tl) & (T_ - 1);
        a_out[r0 + tl] = masks[b * T_ + t] ? a : -(*vsum_p);
    }
}

// ---------------- softmax over T per b ----------------
__global__ __launch_bounds__(256) void k_softmax(const float* __restrict__ a_buf,
                                                 float* __restrict__ r_buf) {
    const int b = blockIdx.x, tid = threadIdx.x;
    const int wave = tid >> 6, lane = tid & 63;
    __shared__ float wred[4];
    float l[8];
    float m = -1e30f;
    #pragma unroll
    for (int i = 0; i < 8; ++i) {
        l[i] = a_buf[b * T_ + tid + 256 * i];
        m = fmaxf(m, l[i]);
    }
    #pragma unroll
    for (int msk = 32; msk; msk >>= 1) m = fmaxf(m, __shfl_xor(m, msk, 64));
    if (lane == 0) wred[wave] = m;
    __syncthreads();
    m = fmaxf(fmaxf(wred[0], wred[1]), fmaxf(wred[2], wred[3]));
    __syncthreads();
    float e[8];
    float s = 0.f;
    #pragma unroll
    for (int i = 0; i < 8; ++i) { e[i] = expf(l[i] - m); s += e[i]; }
    #pragma unroll
    for (int msk = 32; msk; msk >>= 1) s += __shfl_xor(s, msk, 64);
    if (lane == 0) wred[wave] = s;
    __syncthreads();
    s = wred[0] + wred[1] + wred[2] + wred[3];
    const float inv = 1.0f / s;
    #pragma unroll
    for (int i = 0; i < 8; ++i) r_buf[b * T_ + tid + 256 * i] = e[i] * inv;
}

// ---------------- weighted sum over 128-row chunks ----------------
__global__ __launch_bounds__(256) void k_wsum(const float* __restrict__ dec,
                                              const float* __restrict__ r_buf,
                                              float* __restrict__ partials) {
    const int tc = blockIdx.x, b = blockIdx.y, tid = threadIdx.x;
    const float* base = dec + ((size_t)b * T_ + tc * 128) * MID_ + tid * 4;
    const float* rp = r_buf + b * T_ + tc * 128;
    f32x4 acc = {0.f, 0.f, 0.f, 0.f};
    #pragma unroll 4
    for (int i = 0; i < 128; ++i) {
        const float w = rp[i];
        f32x4 d4 = *(const f32x4*)(base + (size_t)i * MID_);
        acc += d4 * w;
    }
    *(f32x4*)(partials + ((b * 16 + tc) * MID_) + tid * 4) = acc;
}

// out[b][m] = sum_tc partials[b][tc][m]
__global__ __launch_bounds__(256) void k_final(const float* __restrict__ partials,
                                               float* __restrict__ out) {
    const int idx = blockIdx.x * 256 + threadIdx.x;  // 0..32767
    const int b = idx >> 10, mcol = idx & 1023;
    float s = 0.f;
    #pragma unroll
    for (int tc = 0; tc < 16; ++tc) s += partials[(b * 16 + tc) * MID_ + mcol];
    out[idx] = s;
}

extern "C" void kernel_launch(void* const* d_in, const int* in_sizes, int n_in,
                              void* d_out, int out_size, void* d_ws, size_t ws_size,
                              hipStream_t stream) {
    const float* enc   = (const float*)d_in[0];
    const float* dec   = (const float*)d_in[1];
    const int*   masks = (const int*)d_in[2];
    const float* Ua_w  = (const float*)d_in[3];
    const float* Ua_b  = (const float*)d_in[4];
    const float* Wa_w  = (const float*)d_in[5];
    const float* v_w   = (const float*)d_in[6];
    float* out = (float*)d_out;

    char* ws = (char*)d_ws;
    float* enc_out  = (float*)(ws + 0);        // 32 KB
    float* vsum     = (float*)(ws + 32768);    // 4 B (padded)
    u16*   wa16s    = (u16*)(ws + 65536);      // 512 KB
    float* a_buf    = (float*)(ws + 589824);   // 256 KB
    float* r_buf    = (float*)(ws + 851968);   // 256 KB
    float* partials = (float*)(ws + 1114112);  // 2 MB

    k_enc<<<dim3(B_), dim3(256), 0, stream>>>(enc, Ua_w, Ua_b, enc_out);
    k_vsum<<<dim3(1), dim3(64), 0, stream>>>(v_w, vsum);
    k_wacvt<<<dim3(256), dim3(256), 0, stream>>>(Wa_w, wa16s);
    k_logits2<<<dim3((B_ * T_) / MBLK_), dim3(512), 0, stream>>>(dec, masks, enc_out,
                                                                 v_w, vsum, wa16s, a_buf);
    k_softmax<<<dim3(B_), dim3(256), 0, stream>>>(a_buf, r_buf);
    k_wsum<<<dim3(16, B_), dim3(256), 0, stream>>>(dec, r_buf, partials);
    k_final<<<dim3(128), dim3(256), 0, stream>>>(partials, out);
}